// Round 8
// baseline (116.722 us; speedup 1.0000x reference)
//
#include <hip/hip_runtime.h>
#include <hip/hip_bf16.h>

typedef __attribute__((ext_vector_type(8))) short bf16x8;
typedef __attribute__((ext_vector_type(4))) float f32x4;

#define NEG 0.2f
#define CST 104   // bf16 elems per LDS row (208 B stride)

__device__ __forceinline__ float lrelu(float x) { return x >= 0.0f ? x : NEG * x; }

__device__ __forceinline__ unsigned short f2bf(float x) {
    unsigned u = __builtin_bit_cast(unsigned, x);
    u += 0x7FFFu + ((u >> 16) & 1u);   // RNE
    return (unsigned short)(u >> 16);
}
// packed pair via v_cvt_pk_bf16_f32 (RNE): low 16 = a, high 16 = b
__device__ __forceinline__ unsigned pk2(float a, float b) {
    __hip_bfloat162 h = __float22bfloat162_rn(float2{a, b});
    unsigned r;
    __builtin_memcpy(&r, &h, sizeof(r));
    return r;
}

__device__ __forceinline__ void red16(f32x4& v) {   // sum over the 16 lr lanes
#pragma unroll
    for (int d = 1; d < 16; d <<= 1) {
        v.x += __shfl_xor(v.x, d);
        v.y += __shfl_xor(v.y, d);
        v.z += __shfl_xor(v.z, d);
        v.w += __shfl_xor(v.w, d);
    }
}

// One block per t. 256 threads = 4 waves. 3 blocks/CU (LDS 47936 B).
// LDS: P  [112][104] bf16 @0     : X -> W_h -> E (per head)
//      HT [112][104] bf16 @23296 : H^T[o][j] per head
//      stats @46592: sas[112] sad[112] ssum[112] (f32)
//      sOut f32 [112][104] overlay at the end.
// Head loop: 4 barriers (was 6); logits in-register from GEMM-1 C-frags;
// single exp pass (unnormalized E), normalization folded into PV accumulate.
extern "C" __global__ void __launch_bounds__(256, 3)
gat7(const float* __restrict__ A, const float* __restrict__ W,
     const float* __restrict__ att_src, const float* __restrict__ att_dst,
     const float* __restrict__ bias, float* __restrict__ out)
{
    extern __shared__ char smem[];
    unsigned short* P  = (unsigned short*)smem;
    unsigned short* HT = (unsigned short*)(smem + 23296);
    float* sas  = (float*)(smem + 46592);
    float* sad  = sas  + 112;
    float* ssum = sad  + 112;
    float* sOut = (float*)smem;

    const int t    = blockIdx.x;
    const int tid  = threadIdx.x;
    const int w    = tid >> 6;
    const int l    = tid & 63;
    const int lr   = l & 15;
    const int lk   = l >> 4;
    const bool HAS2 = (w < 3);
    const int row0 = w;
    const int row1 = HAS2 ? (w + 4) : w;       // wave 3 duplicates (writes suppressed)
    const int j00  = row0 * 16 + 4 * lk;       // <= 60
    const int j01  = row1 * 16 + 4 * lk;       // <= 108
    const float* __restrict__ At = A + (size_t)t * 10000u;

    // zero P (X pads must be 0)
    for (int i = tid; i < 1456; i += 256) ((f32x4*)smem)[i] = (f32x4){0, 0, 0, 0};
    __syncthreads();

    // stage A_t^T -> P[n][f] bf16
    for (int q = tid; q < 2500; q += 256) {
        int f = q / 25, n0 = (q - f * 25) * 4;
        float4 v = *(const float4*)(At + f * 100 + n0);
        P[(n0 + 0) * CST + f] = f2bf(v.x);
        P[(n0 + 1) * CST + f] = f2bf(v.y);
        P[(n0 + 2) * CST + f] = f2bf(v.z);
        P[(n0 + 3) * CST + f] = f2bf(v.w);
    }
    __syncthreads();

    // hoist X fragments (static indices)
    const bf16x8 zf = {0, 0, 0, 0, 0, 0, 0, 0};
    bf16x8 xf[2][4];
#pragma unroll
    for (int ks = 0; ks < 4; ++ks) {
        const bool kill = (ks == 3) && (lk != 0);
        const int koff = kill ? 96 : ks * 32 + lk * 8;
        bf16x8 v0 = *(const bf16x8*)(P + (row0 * 16 + lr) * CST + koff);
        bf16x8 v1 = *(const bf16x8*)(P + (row1 * 16 + lr) * CST + koff);
        xf[0][ks] = kill ? zf : v0;
        xf[1][ks] = kill ? zf : v1;
    }

    f32x4 acc[2][7];
#pragma unroll
    for (int r = 0; r < 2; ++r)
#pragma unroll
        for (int c = 0; c < 7; ++c) acc[r][c] = (f32x4){0, 0, 0, 0};

    for (int h = 0; h < 4; ++h) {
        __syncthreads();   // (1) xf hoisted / prev PV done -> P, ssum reusable

        // ---- Wfill: W_h -> P bf16 via cvt_pk (pads zero); zero ssum ----
        for (int q = tid; q < 2912; q += 256) {
            int o = q / 26, f0 = (q - o * 26) * 4;
            uint2 pp = {0u, 0u};
            if (o < 100 && f0 < 100) {
                float4 wv = *(const float4*)(W + (h * 100 + o) * 100 + f0);
                pp.x = pk2(wv.x, wv.y);
                pp.y = pk2(wv.z, wv.w);
            }
            *(uint2*)(P + o * CST + f0) = pp;
        }
        if (tid < 112) ssum[tid] = 0.0f;
        __syncthreads();   // (2) W ready

        // ---- GEMM-1 (+ in-register logits partials) ----
        f32x4 pS0 = {0,0,0,0}, pD0 = {0,0,0,0}, pS1 = {0,0,0,0}, pD1 = {0,0,0,0};
#pragma unroll
        for (int half = 0; half < 2; ++half) {
            const int ntn = half ? 3 : 4;
            f32x4 c0[4], c1[4];
#pragma unroll
            for (int c = 0; c < 4; ++c) { c0[c] = (f32x4){0,0,0,0}; c1[c] = (f32x4){0,0,0,0}; }
#pragma unroll
            for (int ks = 0; ks < 4; ++ks) {
                const bool kill = (ks == 3) && (lk != 0);
                const int koff = kill ? 96 : ks * 32 + lk * 8;
                bf16x8 b[4];
#pragma unroll
                for (int bb = 0; bb < 4; ++bb)
                    if (bb < ntn) {
                        bf16x8 v = *(const bf16x8*)(P + ((half * 4 + bb) * 16 + lr) * CST + koff);
                        b[bb] = kill ? zf : v;
                    }
#pragma unroll
                for (int bb = 0; bb < 4; ++bb)
                    if (bb < ntn) {
                        c0[bb] = __builtin_amdgcn_mfma_f32_16x16x32_bf16(xf[0][ks], b[bb], c0[bb], 0, 0, 0);
                        c1[bb] = __builtin_amdgcn_mfma_f32_16x16x32_bf16(xf[1][ks], b[bb], c1[bb], 0, 0, 0);
                    }
            }
            // logits partials: a_s[j] += H[j][o]*att_s[o] for this half's o's
#pragma unroll
            for (int bb = 0; bb < 4; ++bb)
                if (bb < ntn) {
                    const int o = (half * 4 + bb) * 16 + lr;
                    const bool vv = (o < 100);
                    const float aS = vv ? att_src[h * 100 + o] : 0.0f;
                    const float aD = vv ? att_dst[h * 100 + o] : 0.0f;
                    pS0 += c0[bb] * aS;  pD0 += c0[bb] * aD;
                    pS1 += c1[bb] * aS;  pD1 += c1[bb] * aD;
                }
            // HT[o][j] writes (cvt_pk pairs)
            {
#pragma unroll
                for (int bb = 0; bb < 4; ++bb)
                    if (bb < ntn) {
                        const int o = (half * 4 + bb) * 16 + lr;
                        uint2 pp;
                        pp.x = pk2(c0[bb].x, c0[bb].y);
                        pp.y = pk2(c0[bb].z, c0[bb].w);
                        *(uint2*)(HT + o * CST + j00) = pp;
                    }
            }
            if (HAS2 && j01 < 104) {
#pragma unroll
                for (int bb = 0; bb < 4; ++bb)
                    if (bb < ntn) {
                        const int o = (half * 4 + bb) * 16 + lr;
                        uint2 pp;
                        pp.x = pk2(c1[bb].x, c1[bb].y);
                        pp.y = pk2(c1[bb].z, c1[bb].w);
                        *(uint2*)(HT + o * CST + j01) = pp;
                    }
            }
        }
        // cross-lane reduce over lr; lane 0 of each lr-group writes sas/sad
        red16(pS0); red16(pD0); red16(pS1); red16(pD1);
        if (lr == 0) {
            *(f32x4*)(sas + j00) = pS0;
            *(f32x4*)(sad + j00) = pD0;
            if (HAS2) {
                *(f32x4*)(sas + j01) = pS1;
                *(f32x4*)(sad + j01) = pD1;
            }
        }
        __syncthreads();   // (3) HT + sas/sad ready

        // ---- E (unnormalized) -> P, row sums -> ssum (single exp pass) ----
        if (tid < 200) {
            const int i = tid >> 1, j0 = (tid & 1) * 50;
            const float adi = sad[i];
            unsigned* dst = (unsigned*)(P + i * CST + j0);
            float sum = 0.0f;
            for (int jj = 0; jj < 50; jj += 2) {
                float e0 = __expf(lrelu(adi + sas[j0 + jj]));
                float e1 = __expf(lrelu(adi + sas[j0 + jj + 1]));
                sum += e0 + e1;
                dst[jj >> 1] = pk2(e0, e1);
            }
            atomicAdd(&ssum[i], sum);
        }
        __syncthreads();   // (4) E + ssum ready

        // ---- PV: acc += (E * H) * inv(ssum), chunked cp (static idx) ----
        f32x4 sv0 = *(const f32x4*)(ssum + j00);
        f32x4 sv1 = *(const f32x4*)(ssum + j01);
        f32x4 inv0, inv1;
        inv0.x = sv0.x > 0.0f ? __builtin_amdgcn_rcpf(sv0.x) : 0.0f;
        inv0.y = sv0.y > 0.0f ? __builtin_amdgcn_rcpf(sv0.y) : 0.0f;
        inv0.z = sv0.z > 0.0f ? __builtin_amdgcn_rcpf(sv0.z) : 0.0f;
        inv0.w = sv0.w > 0.0f ? __builtin_amdgcn_rcpf(sv0.w) : 0.0f;
        inv1.x = sv1.x > 0.0f ? __builtin_amdgcn_rcpf(sv1.x) : 0.0f;
        inv1.y = sv1.y > 0.0f ? __builtin_amdgcn_rcpf(sv1.y) : 0.0f;
        inv1.z = sv1.z > 0.0f ? __builtin_amdgcn_rcpf(sv1.z) : 0.0f;
        inv1.w = sv1.w > 0.0f ? __builtin_amdgcn_rcpf(sv1.w) : 0.0f;
#pragma unroll
        for (int half = 0; half < 2; ++half) {
            const int ntn = half ? 3 : 4;
            f32x4 cp0[4], cp1[4];
#pragma unroll
            for (int c = 0; c < 4; ++c) { cp0[c] = (f32x4){0,0,0,0}; cp1[c] = (f32x4){0,0,0,0}; }
#pragma unroll
            for (int ks = 0; ks < 4; ++ks) {
                const bool kill = (ks == 3) && (lk != 0);
                const int koff = kill ? 96 : ks * 32 + lk * 8;
                bf16x8 a0 = *(const bf16x8*)(P + (row0 * 16 + lr) * CST + koff);
                bf16x8 a1 = *(const bf16x8*)(P + (row1 * 16 + lr) * CST + koff);
                a0 = kill ? zf : a0;
                a1 = kill ? zf : a1;
                bf16x8 b[4];
#pragma unroll
                for (int bb = 0; bb < 4; ++bb)
                    if (bb < ntn) {
                        bf16x8 v = *(const bf16x8*)(HT + ((half * 4 + bb) * 16 + lr) * CST + koff);
                        b[bb] = kill ? zf : v;
                    }
#pragma unroll
                for (int bb = 0; bb < 4; ++bb)
                    if (bb < ntn) {
                        cp0[bb] = __builtin_amdgcn_mfma_f32_16x16x32_bf16(a0, b[bb], cp0[bb], 0, 0, 0);
                        cp1[bb] = __builtin_amdgcn_mfma_f32_16x16x32_bf16(a1, b[bb], cp1[bb], 0, 0, 0);
                    }
            }
#pragma unroll
            for (int bb = 0; bb < 4; ++bb)
                if (bb < ntn) {
                    acc[0][half * 4 + bb] += cp0[bb] * inv0;
                    acc[1][half * 4 + bb] += cp1[bb] * inv1;
                }
        }
    }
    __syncthreads();   // all PV done; P+HT dead -> sOut overlay

    // ---- epilogue: sOut[o][i] = lrelu(acc*0.25 + bias[o]) + (i==o) ----
    {
        const int i0 = j00;
#pragma unroll
        for (int tn = 0; tn < 7; ++tn) {
            const int o = tn * 16 + lr;
            const float b = (o < 100) ? bias[o] : 0.0f;
            f32x4 v;
            v.x = lrelu(acc[0][tn].x * 0.25f + b) + ((i0 + 0) == o ? 1.0f : 0.0f);
            v.y = lrelu(acc[0][tn].y * 0.25f + b) + ((i0 + 1) == o ? 1.0f : 0.0f);
            v.z = lrelu(acc[0][tn].z * 0.25f + b) + ((i0 + 2) == o ? 1.0f : 0.0f);
            v.w = lrelu(acc[0][tn].w * 0.25f + b) + ((i0 + 3) == o ? 1.0f : 0.0f);
            *(f32x4*)(sOut + o * 104 + i0) = v;
        }
    }
    if (HAS2 && j01 < 104) {
        const int i0 = j01;
#pragma unroll
        for (int tn = 0; tn < 7; ++tn) {
            const int o = tn * 16 + lr;
            const float b = (o < 100) ? bias[o] : 0.0f;
            f32x4 v;
            v.x = lrelu(acc[1][tn].x * 0.25f + b) + ((i0 + 0) == o ? 1.0f : 0.0f);
            v.y = lrelu(acc[1][tn].y * 0.25f + b) + ((i0 + 1) == o ? 1.0f : 0.0f);
            v.z = lrelu(acc[1][tn].z * 0.25f + b) + ((i0 + 2) == o ? 1.0f : 0.0f);
            v.w = lrelu(acc[1][tn].w * 0.25f + b) + ((i0 + 3) == o ? 1.0f : 0.0f);
            *(f32x4*)(sOut + o * 104 + i0) = v;
        }
    }
    __syncthreads();

    // ---- coalesced store out[t][o][i] ----
    float* __restrict__ outT = out + (size_t)t * 10000u;
    for (int q = tid; q < 2500; q += 256) {
        int o = q / 25, i0 = (q - o * 25) * 4;
        *(float4*)(outT + o * 100 + i0) = *(const float4*)(sOut + o * 104 + i0);
    }
}

extern "C" void kernel_launch(void* const* d_in, const int* in_sizes, int n_in,
                              void* d_out, int out_size, void* d_ws, size_t ws_size,
                              hipStream_t stream) {
    const float* A      = (const float*)d_in[0];
    const float* W      = (const float*)d_in[1];
    const float* attsrc = (const float*)d_in[2];
    const float* attdst = (const float*)d_in[3];
    const float* bias   = (const float*)d_in[4];
    float* outp = (float*)d_out;

    const int T = in_sizes[0] / 10000;   // 1024
    const int smem_bytes = 47936;
    gat7<<<T, 256, smem_bytes, stream>>>(A, W, attsrc, attdst, bias, outp);
}

// Round 9
// 93.219 us; speedup vs baseline: 1.2521x; 1.2521x over previous
//
#include <hip/hip_runtime.h>
#include <hip/hip_bf16.h>

typedef __attribute__((ext_vector_type(8))) short bf16x8;
typedef __attribute__((ext_vector_type(4))) float f32x4;

#define NEG 0.2f
#define CST 104   // bf16 elems per LDS row (208 B stride)

__device__ __forceinline__ float lrelu(float x) { return x >= 0.0f ? x : NEG * x; }

__device__ __forceinline__ unsigned short f2bf(float x) {
    unsigned u = __builtin_bit_cast(unsigned, x);
    u += 0x7FFFu + ((u >> 16) & 1u);   // RNE
    return (unsigned short)(u >> 16);
}
// packed pair via v_cvt_pk_bf16_f32 (RNE): low 16 = a, high 16 = b
__device__ __forceinline__ unsigned pk2(float a, float b) {
    __hip_bfloat162 h = __float22bfloat162_rn(float2{a, b});
    unsigned r;
    __builtin_memcpy(&r, &h, sizeof(r));
    return r;
}

__device__ __forceinline__ void red16(f32x4& v) {   // sum over 16-lane lr groups
#pragma unroll
    for (int d = 1; d < 16; d <<= 1) {
        v.x += __shfl_xor(v.x, d);
        v.y += __shfl_xor(v.y, d);
        v.z += __shfl_xor(v.z, d);
        v.w += __shfl_xor(v.w, d);
    }
}

// One block per t. 512 threads = 8 waves, ONE 16-row tile per wave
// (wave 7 duplicates row 6, writes suppressed). 2 blocks/CU (LDS 47936 B).
// LDS: P  [112][104] bf16 @0     : X -> W_h -> E (per head)
//      HT [112][104] bf16 @23296 : H^T[o][j] per head
//      stats @46592: sas[112] sad[112] ssum[112] (f32)
//      sOut f32 [112][104] overlay at the end.
// 4 barriers/head; logits in-register from GEMM-1 C-frags; single exp pass
// (unnormalized E), normalization folded into the PV->acc accumulate.
extern "C" __global__ void __launch_bounds__(512, 4)
gat8(const float* __restrict__ A, const float* __restrict__ W,
     const float* __restrict__ att_src, const float* __restrict__ att_dst,
     const float* __restrict__ bias, float* __restrict__ out)
{
    extern __shared__ char smem[];
    unsigned short* P  = (unsigned short*)smem;
    unsigned short* HT = (unsigned short*)(smem + 23296);
    float* sas  = (float*)(smem + 46592);
    float* sad  = sas  + 112;
    float* ssum = sad  + 112;
    float* sOut = (float*)smem;

    const int t    = blockIdx.x;
    const int tid  = threadIdx.x;      // 0..511
    const int w    = tid >> 6;         // 0..7
    const int l    = tid & 63;
    const int lr   = l & 15;
    const int lk   = l >> 4;
    const bool HASW = (w < 7);
    const int row  = HASW ? w : 6;     // wave 7 duplicates row-tile 6
    const int j0   = row * 16 + 4 * lk;        // 0..108
    const bool JW  = HASW && (j0 < 104);       // LDS-write guard
    const float* __restrict__ At = A + (size_t)t * 10000u;

    // zero P (X pads must be 0)
    for (int i = tid; i < 1456; i += 512) ((f32x4*)smem)[i] = (f32x4){0, 0, 0, 0};
    __syncthreads();

    // stage A_t^T -> P[n][f] bf16
    for (int q = tid; q < 2500; q += 512) {
        int f = q / 25, n0 = (q - f * 25) * 4;
        float4 v = *(const float4*)(At + f * 100 + n0);
        P[(n0 + 0) * CST + f] = f2bf(v.x);
        P[(n0 + 1) * CST + f] = f2bf(v.y);
        P[(n0 + 2) * CST + f] = f2bf(v.z);
        P[(n0 + 3) * CST + f] = f2bf(v.w);
    }
    __syncthreads();

    // hoist X fragments (one row-tile per wave)
    const bf16x8 zf = {0, 0, 0, 0, 0, 0, 0, 0};
    bf16x8 xf[4];
#pragma unroll
    for (int ks = 0; ks < 4; ++ks) {
        const bool kill = (ks == 3) && (lk != 0);
        const int koff = kill ? 96 : ks * 32 + lk * 8;
        bf16x8 v = *(const bf16x8*)(P + (row * 16 + lr) * CST + koff);
        xf[ks] = kill ? zf : v;
    }

    f32x4 acc[7];
#pragma unroll
    for (int c = 0; c < 7; ++c) acc[c] = (f32x4){0, 0, 0, 0};

    for (int h = 0; h < 4; ++h) {
        __syncthreads();   // (1) xf hoisted / prev PV done -> P, ssum reusable

        // ---- Wfill: W_h -> P bf16 via cvt_pk (pads zero); zero ssum ----
        for (int q = tid; q < 2912; q += 512) {
            int o = q / 26, f0 = (q - o * 26) * 4;
            uint2 pp = {0u, 0u};
            if (o < 100 && f0 < 100) {
                float4 wv = *(const float4*)(W + (h * 100 + o) * 100 + f0);
                pp.x = pk2(wv.x, wv.y);
                pp.y = pk2(wv.z, wv.w);
            }
            *(uint2*)(P + o * CST + f0) = pp;
        }
        if (tid < 112) ssum[tid] = 0.0f;
        __syncthreads();   // (2) W ready

        // ---- GEMM-1 (+ in-register logits partials), two N-halves ----
        f32x4 pS = {0, 0, 0, 0}, pD = {0, 0, 0, 0};
#pragma unroll
        for (int half = 0; half < 2; ++half) {
            const int ntn = half ? 3 : 4;
            f32x4 c[4];
#pragma unroll
            for (int cc = 0; cc < 4; ++cc) c[cc] = (f32x4){0, 0, 0, 0};
#pragma unroll
            for (int ks = 0; ks < 4; ++ks) {
                const bool kill = (ks == 3) && (lk != 0);
                const int koff = kill ? 96 : ks * 32 + lk * 8;
                bf16x8 b[4] = {zf, zf, zf, zf};
#pragma unroll
                for (int bb = 0; bb < 4; ++bb)
                    if (bb < ntn) {
                        bf16x8 v = *(const bf16x8*)(P + ((half * 4 + bb) * 16 + lr) * CST + koff);
                        b[bb] = kill ? zf : v;
                    }
#pragma unroll
                for (int bb = 0; bb < 4; ++bb)
                    if (bb < ntn)
                        c[bb] = __builtin_amdgcn_mfma_f32_16x16x32_bf16(xf[ks], b[bb], c[bb], 0, 0, 0);
            }
#pragma unroll
            for (int bb = 0; bb < 4; ++bb)
                if (bb < ntn) {
                    const int o = (half * 4 + bb) * 16 + lr;
                    const bool vv = (o < 100);
                    const float aS = vv ? att_src[h * 100 + o] : 0.0f;
                    const float aD = vv ? att_dst[h * 100 + o] : 0.0f;
                    pS += c[bb] * aS;
                    pD += c[bb] * aD;
                    if (JW) {
                        uint2 pp;
                        pp.x = pk2(c[bb].x, c[bb].y);
                        pp.y = pk2(c[bb].z, c[bb].w);
                        *(uint2*)(HT + o * CST + j0) = pp;
                    }
                }
        }
        red16(pS); red16(pD);
        if (JW && lr == 0) {
            *(f32x4*)(sas + j0) = pS;
            *(f32x4*)(sad + j0) = pD;
        }
        __syncthreads();   // (3) HT + sas/sad ready

        // ---- E (unnormalized) -> P, row sums -> ssum (400 threads, quarters) ----
        if (tid < 400) {
            const int i = tid >> 2, qt = tid & 3;
            const int js = qt * 26;
            const int len = (qt == 3) ? 22 : 26;
            const float adi = sad[i];
            unsigned* dst = (unsigned*)(P + i * CST + js);
            float sum = 0.0f;
            for (int jj = 0; jj < len; jj += 2) {
                float e0 = __expf(lrelu(adi + sas[js + jj]));
                float e1 = __expf(lrelu(adi + sas[js + jj + 1]));
                sum += e0 + e1;
                dst[jj >> 1] = pk2(e0, e1);
            }
            atomicAdd(&ssum[i], sum);
        }
        __syncthreads();   // (4) E + ssum ready

        // ---- PV: acc += (E * H) * inv(ssum), two N-halves ----
        f32x4 sv = *(const f32x4*)(ssum + j0);
        f32x4 inv;
        inv.x = sv.x > 0.0f ? __builtin_amdgcn_rcpf(sv.x) : 0.0f;
        inv.y = sv.y > 0.0f ? __builtin_amdgcn_rcpf(sv.y) : 0.0f;
        inv.z = sv.z > 0.0f ? __builtin_amdgcn_rcpf(sv.z) : 0.0f;
        inv.w = sv.w > 0.0f ? __builtin_amdgcn_rcpf(sv.w) : 0.0f;
#pragma unroll
        for (int half = 0; half < 2; ++half) {
            const int ntn = half ? 3 : 4;
            f32x4 cp[4];
#pragma unroll
            for (int cc = 0; cc < 4; ++cc) cp[cc] = (f32x4){0, 0, 0, 0};
#pragma unroll
            for (int ks = 0; ks < 4; ++ks) {
                const bool kill = (ks == 3) && (lk != 0);
                const int koff = kill ? 96 : ks * 32 + lk * 8;
                bf16x8 a = *(const bf16x8*)(P + (row * 16 + lr) * CST + koff);
                a = kill ? zf : a;
                bf16x8 b[4] = {zf, zf, zf, zf};
#pragma unroll
                for (int bb = 0; bb < 4; ++bb)
                    if (bb < ntn) {
                        bf16x8 v = *(const bf16x8*)(HT + ((half * 4 + bb) * 16 + lr) * CST + koff);
                        b[bb] = kill ? zf : v;
                    }
#pragma unroll
                for (int bb = 0; bb < 4; ++bb)
                    if (bb < ntn)
                        cp[bb] = __builtin_amdgcn_mfma_f32_16x16x32_bf16(a, b[bb], cp[bb], 0, 0, 0);
            }
#pragma unroll
            for (int bb = 0; bb < 4; ++bb)
                if (bb < ntn) acc[half * 4 + bb] += cp[bb] * inv;
        }
    }
    __syncthreads();   // all PV done; P+HT dead -> sOut overlay

    // ---- epilogue: sOut[o][i] = lrelu(acc*0.25 + bias[o]) + (i==o) ----
    if (JW) {
        const int i0 = j0;
#pragma unroll
        for (int tn = 0; tn < 7; ++tn) {
            const int o = tn * 16 + lr;
            const float b = (o < 100) ? bias[o] : 0.0f;
            f32x4 v;
            v.x = lrelu(acc[tn].x * 0.25f + b) + ((i0 + 0) == o ? 1.0f : 0.0f);
            v.y = lrelu(acc[tn].y * 0.25f + b) + ((i0 + 1) == o ? 1.0f : 0.0f);
            v.z = lrelu(acc[tn].z * 0.25f + b) + ((i0 + 2) == o ? 1.0f : 0.0f);
            v.w = lrelu(acc[tn].w * 0.25f + b) + ((i0 + 3) == o ? 1.0f : 0.0f);
            *(f32x4*)(sOut + o * 104 + i0) = v;
        }
    }
    __syncthreads();

    // ---- coalesced store out[t][o][i] ----
    float* __restrict__ outT = out + (size_t)t * 10000u;
    for (int q = tid; q < 2500; q += 512) {
        int o = q / 25, i0 = (q - o * 25) * 4;
        *(float4*)(outT + o * 100 + i0) = *(const float4*)(sOut + o * 104 + i0);
    }
}

extern "C" void kernel_launch(void* const* d_in, const int* in_sizes, int n_in,
                              void* d_out, int out_size, void* d_ws, size_t ws_size,
                              hipStream_t stream) {
    const float* A      = (const float*)d_in[0];
    const float* W      = (const float*)d_in[1];
    const float* attsrc = (const float*)d_in[2];
    const float* attdst = (const float*)d_in[3];
    const float* bias   = (const float*)d_in[4];
    float* outp = (float*)d_out;

    const int T = in_sizes[0] / 10000;   // 1024
    const int smem_bytes = 47936;
    gat8<<<T, 512, smem_bytes, stream>>>(A, W, attsrc, attdst, bias, outp);
}

// Round 10
// 80.738 us; speedup vs baseline: 1.4457x; 1.1546x over previous
//
#include <hip/hip_runtime.h>
#include <hip/hip_bf16.h>

typedef __attribute__((ext_vector_type(8))) short bf16x8;
typedef __attribute__((ext_vector_type(4))) float f32x4;
typedef __attribute__((ext_vector_type(4))) unsigned u32x4;

#define NEG 0.2f
#define CST 104   // bf16 elems per LDS row (208 B stride; 52dw%32=20 -> clean bank spread)

__device__ __forceinline__ float lrelu(float x) { return x >= 0.0f ? x : NEG * x; }

__device__ __forceinline__ unsigned short f2bf(float x) {
    unsigned u = __builtin_bit_cast(unsigned, x);
    u += 0x7FFFu + ((u >> 16) & 1u);   // RNE
    return (unsigned short)(u >> 16);
}
// packed pair via v_cvt_pk_bf16_f32 (RNE): low 16 = a, high 16 = b
__device__ __forceinline__ unsigned pk2(float a, float b) {
    __hip_bfloat162 h = __float22bfloat162_rn(float2{a, b});
    unsigned r;
    __builtin_memcpy(&r, &h, sizeof(r));
    return r;
}

__device__ __forceinline__ void red16(f32x4& v) {   // sum over 16-lane lr groups
#pragma unroll
    for (int d = 1; d < 16; d <<= 1) {
        v.x += __shfl_xor(v.x, d);
        v.y += __shfl_xor(v.y, d);
        v.z += __shfl_xor(v.z, d);
        v.w += __shfl_xor(v.w, d);
    }
}

// One block per t. 512 threads = 8 waves, one 16-row tile per wave (wave 7
// duplicates tile 6, writes suppressed). 2 blocks/CU (LDS 47488 B).
// LDS: P  [112][104] bf16 @0     : X (until xf hoisted) -> W_h per head
//      HT [112][104] bf16 @23296 : H^T[o][j] per head
//      stats @46592: sas[112] sad[112] (f32); sas[100..111] = -1e30 (pad kill)
//      sOut f32 [112][104] overlay at the end.
// 2 barriers/head. Logits in-register from GEMM-1 C-frags (red16).
// E computed IN-REGISTER inside PV prep: per lane 32 exps for its own A-frag
// rows; ssum via 2 shfl_xor; normalized before pk2 -> PV MFMAs accumulate
// directly into acc (no E phase, no atomics, no post-scale).
extern "C" __global__ void __launch_bounds__(512, 4)
gat9(const float* __restrict__ A, const float* __restrict__ W,
     const float* __restrict__ att_src, const float* __restrict__ att_dst,
     const float* __restrict__ bias, float* __restrict__ out)
{
    extern __shared__ char smem[];
    unsigned short* P  = (unsigned short*)smem;
    unsigned short* HT = (unsigned short*)(smem + 23296);
    float* sas  = (float*)(smem + 46592);
    float* sad  = sas + 112;
    float* sOut = (float*)smem;

    const int t    = blockIdx.x;
    const int tid  = threadIdx.x;      // 0..511
    const int w    = tid >> 6;         // 0..7
    const int l    = tid & 63;
    const int lr   = l & 15;
    const int lk   = l >> 4;
    const bool HASW = (w < 7);
    const int row  = HASW ? w : 6;     // wave 7 duplicates tile 6
    const int j0   = row * 16 + 4 * lk;        // 0..108
    const bool JW  = HASW && (j0 < 104);       // HT/sad/epilogue write guard
    const float* __restrict__ At = A + (size_t)t * 10000u;

    // zero P; init stats: sas[100..111] = -1e30 (kills pad-j exps), rest 0
    for (int i = tid; i < 1456; i += 512) ((f32x4*)smem)[i] = (f32x4){0, 0, 0, 0};
    if (tid < 224) {
        float v = (tid >= 100 && tid < 112) ? -1e30f : 0.0f;
        ((float*)(smem + 46592))[tid] = v;
    }
    __syncthreads();

    // stage A_t^T -> P[n][f] bf16
    for (int q = tid; q < 2500; q += 512) {
        int f = q / 25, n0 = (q - f * 25) * 4;
        float4 v = *(const float4*)(At + f * 100 + n0);
        P[(n0 + 0) * CST + f] = f2bf(v.x);
        P[(n0 + 1) * CST + f] = f2bf(v.y);
        P[(n0 + 2) * CST + f] = f2bf(v.z);
        P[(n0 + 3) * CST + f] = f2bf(v.w);
    }
    __syncthreads();

    // hoist X fragments (A-side zero pads for ks==3, lk!=0)
    const bf16x8 zf = {0, 0, 0, 0, 0, 0, 0, 0};
    bf16x8 xf[4];
#pragma unroll
    for (int ks = 0; ks < 4; ++ks) {
        const bool kill = (ks == 3) && (lk != 0);
        const int koff = kill ? 96 : ks * 32 + lk * 8;
        bf16x8 v = *(const bf16x8*)(P + (row * 16 + lr) * CST + koff);
        xf[ks] = kill ? zf : v;
    }
    __syncthreads();   // hoist done before Wfill_0 overwrites P

    f32x4 acc[7];
#pragma unroll
    for (int c = 0; c < 7; ++c) acc[c] = (f32x4){0, 0, 0, 0};

    for (int h = 0; h < 4; ++h) {
        // ---- Wfill: W_h -> P bf16 via cvt_pk (pads zero) ----
        // (safe without a leading barrier: last P readers were GEMM-1_{h-1},
        //  fenced by that head's post-GEMM barrier; PV doesn't touch P)
        for (int q = tid; q < 2912; q += 512) {
            int o = q / 26, f0 = (q - o * 26) * 4;
            uint2 pp = {0u, 0u};
            if (o < 100 && f0 < 100) {
                float4 wv = *(const float4*)(W + (h * 100 + o) * 100 + f0);
                pp.x = pk2(wv.x, wv.y);
                pp.y = pk2(wv.z, wv.w);
            }
            *(uint2*)(P + o * CST + f0) = pp;
        }
        __syncthreads();   // (b) W ready; also fences PV_{h-1} HT reads

        // ---- GEMM-1 (+ in-register logits partials), two N-halves ----
        f32x4 pS = {0, 0, 0, 0}, pD = {0, 0, 0, 0};
#pragma unroll
        for (int half = 0; half < 2; ++half) {
            const int ntn = half ? 3 : 4;
            f32x4 c[4];
#pragma unroll
            for (int cc = 0; cc < 4; ++cc) c[cc] = (f32x4){0, 0, 0, 0};
#pragma unroll
            for (int ks = 0; ks < 4; ++ks) {
                const int koff = ks * 32 + lk * 8;   // no B-kill: A-side is zero
                bf16x8 b[4];
#pragma unroll
                for (int bb = 0; bb < 4; ++bb)
                    if (bb < ntn)
                        b[bb] = *(const bf16x8*)(P + ((half * 4 + bb) * 16 + lr) * CST + koff);
#pragma unroll
                for (int bb = 0; bb < 4; ++bb)
                    if (bb < ntn)
                        c[bb] = __builtin_amdgcn_mfma_f32_16x16x32_bf16(xf[ks], b[bb], c[bb], 0, 0, 0);
            }
#pragma unroll
            for (int bb = 0; bb < 4; ++bb)
                if (bb < ntn) {
                    const int o = (half * 4 + bb) * 16 + lr;
                    const bool vv = (o < 100);
                    const float aS = vv ? att_src[h * 100 + o] : 0.0f;
                    const float aD = vv ? att_dst[h * 100 + o] : 0.0f;
                    pS += c[bb] * aS;
                    pD += c[bb] * aD;
                    if (JW) {
                        uint2 pp;
                        pp.x = pk2(c[bb].x, c[bb].y);
                        pp.y = pk2(c[bb].z, c[bb].w);
                        *(uint2*)(HT + o * CST + j0) = pp;
                    }
                }
        }
        red16(pS); red16(pD);
        if (lr == 0) {
            if (HASW && j0 < 100) *(f32x4*)(sas + j0) = pS;   // sas[100..103] stays -1e30
            if (JW)               *(f32x4*)(sad + j0) = pD;
        }
        __syncthreads();   // (c) HT + sas/sad ready

        // ---- PV prep: in-register E, normalized (per-lane own rows) ----
        const float adi = sad[row * 16 + lr];
        float ev[32];
        float sE = 0.0f;
#pragma unroll
        for (int ks = 0; ks < 4; ++ks) {
            const bool dead = (ks == 3) && (lk != 0);
            const int jb = dead ? 0 : ks * 32 + lk * 8;
#pragma unroll
            for (int jj = 0; jj < 8; ++jj) {
                float e = dead ? 0.0f : __expf(lrelu(adi + sas[jb + jj]));
                ev[ks * 8 + jj] = e;
                sE += e;
            }
        }
        sE += __shfl_xor(sE, 16);
        sE += __shfl_xor(sE, 32);
        const float invE = sE > 0.0f ? __builtin_amdgcn_rcpf(sE) : 0.0f;
        bf16x8 af[4];
#pragma unroll
        for (int ks = 0; ks < 4; ++ks) {
            u32x4 uv;
            uv.x = pk2(ev[ks * 8 + 0] * invE, ev[ks * 8 + 1] * invE);
            uv.y = pk2(ev[ks * 8 + 2] * invE, ev[ks * 8 + 3] * invE);
            uv.z = pk2(ev[ks * 8 + 4] * invE, ev[ks * 8 + 5] * invE);
            uv.w = pk2(ev[ks * 8 + 6] * invE, ev[ks * 8 + 7] * invE);
            af[ks] = __builtin_bit_cast(bf16x8, uv);
        }

        // ---- PV: acc += alpha * H (direct C accumulation) ----
#pragma unroll
        for (int half = 0; half < 2; ++half) {
            const int ntn = half ? 3 : 4;
#pragma unroll
            for (int ks = 0; ks < 4; ++ks) {
                const int koff = ks * 32 + lk * 8;
                bf16x8 b[4];
#pragma unroll
                for (int bb = 0; bb < 4; ++bb)
                    if (bb < ntn)
                        b[bb] = *(const bf16x8*)(HT + ((half * 4 + bb) * 16 + lr) * CST + koff);
#pragma unroll
                for (int bb = 0; bb < 4; ++bb)
                    if (bb < ntn)
                        acc[half * 4 + bb] = __builtin_amdgcn_mfma_f32_16x16x32_bf16(
                            af[ks], b[bb], acc[half * 4 + bb], 0, 0, 0);
            }
        }
    }
    __syncthreads();   // all PV done; P+HT dead -> sOut overlay

    // ---- epilogue: sOut[o][i] = lrelu(acc*0.25 + bias[o]) + (i==o) ----
    if (JW) {
        const int i0 = j0;
#pragma unroll
        for (int tn = 0; tn < 7; ++tn) {
            const int o = tn * 16 + lr;
            const float b = (o < 100) ? bias[o] : 0.0f;
            f32x4 v;
            v.x = lrelu(acc[tn].x * 0.25f + b) + ((i0 + 0) == o ? 1.0f : 0.0f);
            v.y = lrelu(acc[tn].y * 0.25f + b) + ((i0 + 1) == o ? 1.0f : 0.0f);
            v.z = lrelu(acc[tn].z * 0.25f + b) + ((i0 + 2) == o ? 1.0f : 0.0f);
            v.w = lrelu(acc[tn].w * 0.25f + b) + ((i0 + 3) == o ? 1.0f : 0.0f);
            *(f32x4*)(sOut + o * 104 + i0) = v;
        }
    }
    __syncthreads();

    // ---- coalesced store out[t][o][i] ----
    float* __restrict__ outT = out + (size_t)t * 10000u;
    for (int q = tid; q < 2500; q += 512) {
        int o = q / 25, i0 = (q - o * 25) * 4;
        *(float4*)(outT + o * 100 + i0) = *(const float4*)(sOut + o * 104 + i0);
    }
}

extern "C" void kernel_launch(void* const* d_in, const int* in_sizes, int n_in,
                              void* d_out, int out_size, void* d_ws, size_t ws_size,
                              hipStream_t stream) {
    const float* A      = (const float*)d_in[0];
    const float* W      = (const float*)d_in[1];
    const float* attsrc = (const float*)d_in[2];
    const float* attdst = (const float*)d_in[3];
    const float* bias   = (const float*)d_in[4];
    float* outp = (float*)d_out;

    const int T = in_sizes[0] / 10000;   // 1024
    const int smem_bytes = 47488;
    gat9<<<T, 512, smem_bytes, stream>>>(A, W, attsrc, attdst, bias, outp);
}